// Round 12
// baseline (113.619 us; speedup 1.0000x reference)
//
#include <hip/hip_runtime.h>
#include <hip/hip_bf16.h>
#include <stdint.h>

typedef unsigned short u16;
typedef __bf16 bf16_t;
typedef bf16_t bf16x8 __attribute__((ext_vector_type(8)));
typedef float f32x4 __attribute__((ext_vector_type(4)));
typedef float f32x16 __attribute__((ext_vector_type(16)));

#define MFMA16(a, b, c) __builtin_amdgcn_mfma_f32_16x16x32_bf16((a), (b), (c), 0, 0, 0)
#define MFMA32(a, b, c) __builtin_amdgcn_mfma_f32_32x32x16_bf16((a), (b), (c), 0, 0, 0)

#define NBATCH 8
#define SEQL 1024
#define EMB 1024
#define NHEAD 16
#define HD 64

static __device__ __forceinline__ u16 f2b(float f) {
  bf16_t b = (bf16_t)f;
  return __builtin_bit_cast(u16, b);
}

union V16 { uint4 u; bf16x8 b; };

static __device__ __forceinline__ bf16x8 ldb8(const u16* p) {
  V16 v; v.u = *(const uint4*)p; return v.b;
}

static __device__ __forceinline__ bf16x8 cvt8(const float* p) {
  float4 a = *(const float4*)p;
  float4 b = *(const float4*)(p + 4);
  bf16x8 r;
  r[0] = (bf16_t)a.x; r[1] = (bf16_t)a.y; r[2] = (bf16_t)a.z; r[3] = (bf16_t)a.w;
  r[4] = (bf16_t)b.x; r[5] = (bf16_t)b.y; r[6] = (bf16_t)b.z; r[7] = (bf16_t)b.w;
  return r;
}

// async global -> LDS, 16B per lane; lds ptr must be wave-uniform (HW adds lane*16)
static __device__ __forceinline__ void gload16(const void* g, void* l) {
  __builtin_amdgcn_global_load_lds((__attribute__((address_space(1))) void*)(uintptr_t)g,
                                   (__attribute__((address_space(3))) void*)l, 16, 0, 0);
}

static __device__ __forceinline__ unsigned cvtpk(float lo, float hi) {
  unsigned r;
  asm("v_cvt_pk_bf16_f32 %0, %1, %2" : "=v"(r) : "v"(lo), "v"(hi));
  return r;
}

static __device__ __forceinline__ f32x16 zero16() {
  f32x16 z;
#pragma unroll
  for (int i = 0; i < 16; ++i) z[i] = 0.f;
  return z;
}

// ---------------- per-head projections + Wo convert, one launch (z selects) ----------------
// z=0: V -> Vt2[nh][l>>3][d][l&7]; z=1: K -> Kp[nh][l][d]; z=2: Q*scale -> Qp[nh][l][d];
// z=3: Wo fp32 -> bf16 (pure convert, early return, no barriers)
__global__ __launch_bounds__(256) void k_proj3(const float* __restrict__ Xv, const float* __restrict__ Xk,
                                               const float* __restrict__ Xq, const float* __restrict__ Wv,
                                               const float* __restrict__ Wk, const float* __restrict__ Wq,
                                               u16* __restrict__ Vt, u16* __restrict__ Kp, u16* __restrict__ Qp,
                                               const float* __restrict__ Wo, u16* __restrict__ Wob) {
  int z = blockIdx.z;
  if (z == 3) {   // whole block takes this path: no barrier divergence
    size_t i = ((size_t)blockIdx.x * 256 + threadIdx.x) * 8;
    V16 v; v.b = cvt8(Wo + i);
    *(uint4*)(Wob + i) = v.u;
    return;
  }
  __shared__ __align__(16) u16 xs[16 * 1024];
  __shared__ __align__(16) u16 obuf[4][16 * 72];
  __shared__ __align__(16) u16 ob2[4][1024];
  const float* X = (z == 0) ? Xv : (z == 1) ? Xk : Xq;
  const float* W = (z == 0) ? Wv : (z == 1) ? Wk : Wq;
  u16* Out = (z == 0) ? Vt : (z == 1) ? Kp : Qp;
  int vmode = (z == 0);
  float qs = (z == 2) ? 0.04508422f : 1.0f;   // (1/sqrt(EMB)) * log2(e) folded into Q

  int gr0 = blockIdx.x * 16;
  int n = gr0 >> 10, l0 = gr0 & 1023;
  int tid = threadIdx.x, w = tid >> 6, lane = tid & 63;
  int lr = lane & 15, lg = lane >> 4;

  bf16x8 bw[4][2];
#pragma unroll
  for (int c = 0; c < 4; ++c)
#pragma unroll
    for (int kk = 0; kk < 2; ++kk)
      bw[c][kk] = cvt8(W + (lr + 16 * c) * HD + kk * 32 + lg * 8);

#pragma unroll
  for (int i = 0; i < 8; ++i) {
    int m = i * 256 + tid;
    int row = m >> 7, cc = m & 127;
    V16 v; v.b = cvt8(X + (size_t)gr0 * 1024 + (size_t)m * 8);
    *(uint4*)(xs + row * 1024 + ((cc ^ (row & 7)) * 8)) = v.u;
  }
  __syncthreads();

#pragma unroll 1
  for (int h4 = 0; h4 < 4; ++h4) {
    int h = w * 4 + h4;
    int nh = n * 16 + h;
    bf16x8 a0 = ldb8(xs + lr * 1024 + (((h * 8 + 0 + lg) ^ (lr & 7)) * 8));
    bf16x8 a1 = ldb8(xs + lr * 1024 + (((h * 8 + 4 + lg) ^ (lr & 7)) * 8));
    f32x4 acc[4];
#pragma unroll
    for (int c = 0; c < 4; ++c) {
      f32x4 zz = {0.f, 0.f, 0.f, 0.f};
      zz = MFMA16(a0, bw[c][0], zz);
      zz = MFMA16(a1, bw[c][1], zz);
      acc[c] = zz;
    }
    if (!vmode) {
      u16* ob = obuf[w];
#pragma unroll
      for (int c = 0; c < 4; ++c)
#pragma unroll
        for (int rr = 0; rr < 4; ++rr)
          ob[(lg * 4 + rr) * 72 + lr + 16 * c] = f2b(acc[c][rr] * qs);
      int orow = lane >> 2, oseg = lane & 3;
      uint4 v0 = *(const uint4*)(ob + orow * 72 + oseg * 16);
      uint4 v1 = *(const uint4*)(ob + orow * 72 + oseg * 16 + 8);
      u16* dst = Out + ((size_t)nh * SEQL + l0 + orow) * HD + oseg * 16;
      *(uint4*)dst = v0;
      *(uint4*)(dst + 8) = v1;
    } else {
      u16* o2 = ob2[w];
#pragma unroll
      for (int c = 0; c < 4; ++c) {
        ushort4 p;
        p.x = f2b(acc[c][0]); p.y = f2b(acc[c][1]); p.z = f2b(acc[c][2]); p.w = f2b(acc[c][3]);
        *(ushort4*)(o2 + (lg >> 1) * 512 + (lr + 16 * c) * 8 + (lg & 1) * 4) = p;
      }
      int lb0 = l0 >> 3;
#pragma unroll
      for (int lbi = 0; lbi < 2; ++lbi) {
        uint4 vv = *(const uint4*)(o2 + lbi * 512 + lane * 8);
        *(uint4*)(Out + (size_t)nh * 65536 + (size_t)(lb0 + lbi) * 512 + lane * 8) = vv;
      }
    }
  }
}

// ---------------- fused attention, KV-split by 2 (z = half) ----------------
// Per-wave pipeline byte-identical to R7/R11; each block does 8 KV tiles.
// Linear softmax combine (no max-sub): block emits unnormalized O_s (bf16) + den_s (f32).
// s=0 -> AO buffer, s=1 -> Op1. Grid (128,4,2) = 1024 blocks = 4 blocks/CU.
__global__ __launch_bounds__(256, 2) void k_attn2(const u16* __restrict__ Qp, const u16* __restrict__ Kp,
                                                  const u16* __restrict__ Vt, const int* __restrict__ mask,
                                                  u16* __restrict__ AO, u16* __restrict__ Op1,
                                                  float* __restrict__ den0, float* __restrict__ den1) {
  __shared__ __align__(16) u16 SMEM[2][8192];   // [buf][ K:0..4095 | V:4096..8191 ]
  __shared__ unsigned long long mkb[16];

  int nh = blockIdx.x;
  int n = nh >> 4, h = nh & 15;
  int s = blockIdx.z;
  int kt0 = s * 8;
  int tid = threadIdx.x, w = tid >> 6, lane = tid & 63;
  int q = lane & 31, hi = lane >> 5;
  int q0w = blockIdx.y * 256 + w * 64;

  // Q B-frags for both q-groups (Q pre-scaled)
  bf16x8 bq[2][4];
#pragma unroll
  for (int g = 0; g < 2; ++g) {
    const u16* qbase = Qp + ((size_t)nh * SEQL + q0w + g * 32 + q) * HD + hi * 8;
#pragma unroll
    for (int kk = 0; kk < 4; ++kk) bq[g][kk] = ldb8(qbase + kk * 16);
  }

  const u16* gK = Kp + (size_t)nh * SEQL * HD;
  const u16* gV = Vt + (size_t)nh * HD * SEQL;
  int sr = lane >> 3, sslot = lane & 7;

  auto STAGE = [&](int b, int t) {
#pragma unroll
    for (int j = 0; j < 2; ++j) {
      int r = 16 * w + 8 * j + sr;              // tile row 0..63
      int slot = sslot ^ (r & 7);               // pre-swizzled source chunk
      gload16(gK + ((size_t)(t * 64 + r)) * HD + slot * 8,
              &SMEM[b][w * 1024 + j * 512]);
      // Vt2 chunked: element (d=r, l = t*64 + slot*8 + [0,8)) at (t*8+slot)*512 + r*8
      gload16(gV + (size_t)(t * 8 + slot) * 512 + r * 8,
              &SMEM[b][4096 + w * 1024 + j * 512]);
    }
  };

  STAGE(0, kt0);
#pragma unroll 1
  for (int t = kt0 + w; t < kt0 + 8; t += 4) {
    int mv = mask[n * SEQL + t * 64 + lane];
    unsigned long long b = __ballot(mv != 0);
    if (lane == 0) mkb[t] = b;
  }
  __syncthreads();

  f32x16 oacc[2][2];
  oacc[0][0] = zero16(); oacc[0][1] = zero16();
  oacc[1][0] = zero16(); oacc[1][1] = zero16();
  float lsum0 = 0.f, lsum1 = 0.f;
  int buf = 0;

#pragma unroll 1
  for (int kt = kt0; kt < kt0 + 8; ++kt) {
    if (kt < kt0 + 7) STAGE(buf ^ 1, kt + 1);
    const u16* KB = &SMEM[buf][0];
    const u16* VB = &SMEM[buf][4096];
    unsigned long long mb = mkb[kt];

#pragma unroll
    for (int c = 0; c < 2; ++c) {
      // ---- QK^T quadrant c: lane holds S[kpos=32c+4hi+(rr&3)+8(rr>>2)][q], both groups
      f32x16 s0 = zero16(), s1 = zero16();
      {
        int row = 32 * c + q;
        int swz = (row & 7) << 3;
        const u16* kr = KB + row * 64;
        __builtin_amdgcn_s_setprio(1);
#pragma unroll
        for (int kk = 0; kk < 4; ++kk) {
          bf16x8 ak = ldb8(kr + ((16 * kk + 8 * hi) ^ swz));
          s0 = MFMA32(ak, bq[0][kk], s0);
          s1 = MFMA32(ak, bq[1][kk], s1);
        }
        __builtin_amdgcn_s_setprio(0);
      }

      // ---- exp2 (Q pre-scaled, logits bounded) + mask + local denominator
#pragma unroll
      for (int rr = 0; rr < 16; ++rr) {
        s0[rr] = __builtin_amdgcn_exp2f(s0[rr]);
        s1[rr] = __builtin_amdgcn_exp2f(s1[rr]);
      }
      if (mb != ~0ull) {
#pragma unroll
        for (int rr = 0; rr < 16; ++rr) {
          int kpos = 32 * c + 4 * hi + (rr & 3) + 8 * (rr >> 2);
          if (!((mb >> kpos) & 1)) { s0[rr] = 0.f; s1[rr] = 0.f; }
        }
      }
#pragma unroll
      for (int rr = 0; rr < 16; ++rr) { lsum0 += s0[rr]; lsum1 += s1[rr]; }

      // ---- pack quadrant c to PV A-frags (tq = 2c+p2) via cvt_pk + permlane32_swap
      bf16x8 pa0[2], pa1[2];
#pragma unroll
      for (int p2 = 0; p2 < 2; ++p2) {
        unsigned a0 = cvtpk(s0[8 * p2 + 0], s0[8 * p2 + 1]);
        unsigned a1 = cvtpk(s0[8 * p2 + 2], s0[8 * p2 + 3]);
        unsigned b0 = cvtpk(s0[8 * p2 + 4], s0[8 * p2 + 5]);
        unsigned b1 = cvtpk(s0[8 * p2 + 6], s0[8 * p2 + 7]);
        auto r0 = __builtin_amdgcn_permlane32_swap(a0, b0, false, false);
        auto r1 = __builtin_amdgcn_permlane32_swap(a1, b1, false, false);
        union { unsigned u[4]; bf16x8 v; } pu;
        pu.u[0] = r0[0]; pu.u[1] = r1[0]; pu.u[2] = r0[1]; pu.u[3] = r1[1];
        pa0[p2] = pu.v;
        unsigned c0 = cvtpk(s1[8 * p2 + 0], s1[8 * p2 + 1]);
        unsigned c1 = cvtpk(s1[8 * p2 + 2], s1[8 * p2 + 3]);
        unsigned d0 = cvtpk(s1[8 * p2 + 4], s1[8 * p2 + 5]);
        unsigned d1 = cvtpk(s1[8 * p2 + 6], s1[8 * p2 + 7]);
        auto r2 = __builtin_amdgcn_permlane32_swap(c0, d0, false, false);
        auto r3 = __builtin_amdgcn_permlane32_swap(c1, d1, false, false);
        union { unsigned u[4]; bf16x8 v; } pv;
        pv.u[0] = r2[0]; pv.u[1] = r3[0]; pv.u[2] = r2[1]; pv.u[3] = r3[1];
        pa1[p2] = pv.v;
      }

      // ---- PV for tq in {2c, 2c+1}: V frag shared by both groups
      __builtin_amdgcn_s_setprio(1);
#pragma unroll
      for (int cp = 0; cp < 2; ++cp) {
        int row = 32 * cp + q;                   // d index
        int swz = (row & 7) << 3;
        const u16* vr = VB + row * 64;
#pragma unroll
        for (int p2 = 0; p2 < 2; ++p2) {
          int tq = 2 * c + p2;
          bf16x8 vb = ldb8(vr + ((16 * tq + 8 * hi) ^ swz));
          oacc[0][cp] = MFMA32(pa0[p2], vb, oacc[0][cp]);
          oacc[1][cp] = MFMA32(pa1[p2], vb, oacc[1][cp]);
        }
      }
      __builtin_amdgcn_s_setprio(0);
    }
    __syncthreads();
    buf ^= 1;
  }

  // partial denominators: q-row halves live on lane pair (q, q+32); write f32 to global
  u16* Od = s ? Op1 : AO;
  float* dd = s ? den1 : den0;
  float t0 = lsum0 + __shfl_xor(lsum0, 32);
  float t1 = lsum1 + __shfl_xor(lsum1, 32);
  if (!hi) {
    dd[nh * 1024 + q0w + q] = t0;
    dd[nh * 1024 + q0w + 32 + q] = t1;
  }

  // epilogue per q-group: restage RAW partial O (bf16), coalesced write (fully unrolled; rule #20)
  u16* ob = &SMEM[0][0] + w * 2560;
  int orow = lane >> 1, ohalf = lane & 1;
#pragma unroll
  for (int g = 0; g < 2; ++g) {
#pragma unroll
    for (int cp = 0; cp < 2; ++cp)
#pragma unroll
      for (int rr = 0; rr < 16; ++rr) {
        int qr = (rr & 3) + 8 * (rr >> 2) + 4 * hi;
        ob[qr * 80 + 32 * cp + q] = f2b(oacc[g][cp][rr]);
      }
    __builtin_amdgcn_s_barrier();
    const u16* srcp = ob + orow * 80 + ohalf * 32;
    uint4 v0 = *(const uint4*)srcp;
    uint4 v1 = *(const uint4*)(srcp + 8);
    uint4 v2 = *(const uint4*)(srcp + 16);
    uint4 v3 = *(const uint4*)(srcp + 24);
    u16* dst = Od + ((size_t)(n * SEQL + q0w + g * 32 + orow)) * EMB + h * HD + ohalf * 32;
    *(uint4*)dst = v0;
    *(uint4*)(dst + 8) = v1;
    *(uint4*)(dst + 16) = v2;
    *(uint4*)(dst + 24) = v3;
  }
}

// ---------------- merge KV-split partials: AO = (O0 + O1) / (den0 + den1) ----------------
__global__ __launch_bounds__(256) void k_merge(u16* __restrict__ AO, const u16* __restrict__ Op1,
                                               const float* __restrict__ den0, const float* __restrict__ den1) {
  size_t base = ((size_t)blockIdx.x * 256 + threadIdx.x) * 8;
  int qlin = (int)(base >> 10);     // n*1024 + q
  int e = (int)(base & 1023);
  int h = e >> 6;
  int n = qlin >> 10, q = qlin & 1023;
  int di = (n * 16 + h) * 1024 + q;
  float inv = 1.0f / (den0[di] + den1[di]);
  V16 a; a.u = *(const uint4*)(AO + base);
  V16 b; b.u = *(const uint4*)(Op1 + base);
  V16 o;
#pragma unroll
  for (int j = 0; j < 8; ++j)
    o.b[j] = (bf16_t)(((float)a.b[j] + (float)b.b[j]) * inv);
  *(uint4*)(AO + base) = o.u;
}

// ---------------- output projection: Y = AO (8192x1024) * Wo^T + bo ----------------
__global__ __launch_bounds__(256) void k_out(const u16* __restrict__ AO, const u16* __restrict__ Wob,
                                             const float* __restrict__ bo, float* __restrict__ Y) {
  __shared__ __align__(16) u16 As[2][8192];
  __shared__ __align__(16) u16 Bs[2][8192];
  int g = blockIdx.x;
  int xcd = g & 7, rr_ = g >> 3;
  int m0 = (xcd * 8 + (rr_ >> 3)) * 128;
  int n0 = (rr_ & 7) * 128;
  int tid = threadIdx.x, w = tid >> 6, lane = tid & 63;
  int lr = lane & 15, lg = lane >> 4;
  int wr = w >> 1, wc = w & 1;
  int sr8 = lane >> 3, ss8 = lane & 7;

  auto STAGE = [&](int b, int kb) {
#pragma unroll
    for (int j = 0; j < 4; ++j) {
      int row = 32 * w + 8 * j + sr8;
      gload16(AO + (size_t)(m0 + row) * EMB + kb * 64 + ((ss8 ^ (row & 7)) * 8),
              &As[b][w * 2048 + j * 512]);
      gload16(Wob + (size_t)(n0 + row) * EMB + kb * 64 + ((ss8 ^ (row & 7)) * 8),
              &Bs[b][w * 2048 + j * 512]);
    }
  };

  f32x4 acc[4][4] = {};
  STAGE(0, 0);
  __syncthreads();
  int buf = 0;
#pragma unroll 1
  for (int kb = 0; kb < 16; ++kb) {
    if (kb < 15) STAGE(buf ^ 1, kb + 1);
    bf16x8 a0[4], a1[4], b0[4], b1[4];
#pragma unroll
    for (int mi = 0; mi < 4; ++mi) {
      int row = wr * 64 + mi * 16 + lr;
      a0[mi] = ldb8(&As[buf][row * 64 + (((0 + lg) ^ (row & 7)) * 8)]);
      a1[mi] = ldb8(&As[buf][row * 64 + (((4 + lg) ^ (row & 7)) * 8)]);
    }
#pragma unroll
    for (int ni = 0; ni < 4; ++ni) {
      int row = wc * 64 + ni * 16 + lr;
      b0[ni] = ldb8(&Bs[buf][row * 64 + (((0 + lg) ^ (row & 7)) * 8)]);
      b1[ni] = ldb8(&Bs[buf][row * 64 + (((4 + lg) ^ (row & 7)) * 8)]);
    }
    __builtin_amdgcn_s_setprio(1);
#pragma unroll
    for (int mi = 0; mi < 4; ++mi)
#pragma unroll
      for (int ni = 0; ni < 4; ++ni) {
        acc[mi][ni] = MFMA16(a0[mi], b0[ni], acc[mi][ni]);
        acc[mi][ni] = MFMA16(a1[mi], b1[ni], acc[mi][ni]);
      }
    __builtin_amdgcn_s_setprio(0);
    __syncthreads();
    buf ^= 1;
  }
#pragma unroll
  for (int ni = 0; ni < 4; ++ni) {
    float bov = bo[n0 + wc * 64 + ni * 16 + lr];
#pragma unroll
    for (int mi = 0; mi < 4; ++mi) {
#pragma unroll
      for (int rr = 0; rr < 4; ++rr) {
        int row = m0 + wr * 64 + mi * 16 + lg * 4 + rr;
        int col = n0 + wc * 64 + ni * 16 + lr;
        Y[(size_t)row * EMB + col] = acc[mi][ni][rr] + bov;
      }
    }
  }
}

extern "C" void kernel_launch(void* const* d_in, const int* in_sizes, int n_in,
                              void* d_out, int out_size, void* d_ws, size_t ws_size,
                              hipStream_t stream) {
  (void)in_sizes; (void)n_in; (void)out_size; (void)ws_size;
  const float* values = (const float*)d_in[0];
  const float* keys   = (const float*)d_in[1];
  const float* query  = (const float*)d_in[2];
  const int*   mask   = (const int*)d_in[3];
  const float* Wv = (const float*)d_in[4];
  const float* Wk = (const float*)d_in[5];
  const float* Wq = (const float*)d_in[6];
  const float* Wo = (const float*)d_in[7];
  const float* bo = (const float*)d_in[8];
  float* out = (float*)d_out;

  // workspace (u16 units): Qp@0 | Kp@8M | Vt@16M | AO@24M | Wob@32M | Op1@33M | den0@41M | den1@41.5M
  u16* ws   = (u16*)d_ws;
  u16* Qp   = ws;
  u16* Kp   = ws + (size_t)8 * 1024 * 1024;
  u16* Vt   = ws + (size_t)16 * 1024 * 1024;
  u16* AO   = ws + (size_t)24 * 1024 * 1024;
  u16* Wob  = ws + (size_t)32 * 1024 * 1024;
  u16* Op1  = ws + (size_t)33 * 1024 * 1024;
  float* den0 = (float*)(ws + (size_t)41 * 1024 * 1024);
  float* den1 = (float*)(ws + (size_t)41 * 1024 * 1024 + 512 * 1024);

  k_proj3<<<dim3(512, 1, 4), dim3(256), 0, stream>>>(values, keys, query, Wv, Wk, Wq, Vt, Kp, Qp, Wo, Wob);
  k_attn2<<<dim3(128, 4, 2), dim3(256), 0, stream>>>(Qp, Kp, Vt, mask, AO, Op1, den0, den1);
  k_merge<<<dim3(4096), dim3(256), 0, stream>>>(AO, Op1, den0, den1);
  k_out<<<dim3(512), dim3(256), 0, stream>>>(AO, Wob, bo, out);
}

// Round 13
// 97.547 us; speedup vs baseline: 1.1648x; 1.1648x over previous
//
#include <hip/hip_runtime.h>
#include <hip/hip_bf16.h>
#include <stdint.h>

typedef unsigned short u16;
typedef __bf16 bf16_t;
typedef bf16_t bf16x8 __attribute__((ext_vector_type(8)));
typedef float f32x4 __attribute__((ext_vector_type(4)));
typedef float f32x16 __attribute__((ext_vector_type(16)));

#define MFMA16(a, b, c) __builtin_amdgcn_mfma_f32_16x16x32_bf16((a), (b), (c), 0, 0, 0)
#define MFMA32(a, b, c) __builtin_amdgcn_mfma_f32_32x32x16_bf16((a), (b), (c), 0, 0, 0)

#define NBATCH 8
#define SEQL 1024
#define EMB 1024
#define NHEAD 16
#define HD 64

static __device__ __forceinline__ u16 f2b(float f) {
  bf16_t b = (bf16_t)f;
  return __builtin_bit_cast(u16, b);
}

union V16 { uint4 u; bf16x8 b; };

static __device__ __forceinline__ bf16x8 ldb8(const u16* p) {
  V16 v; v.u = *(const uint4*)p; return v.b;
}

static __device__ __forceinline__ bf16x8 cvt8(const float* p) {
  float4 a = *(const float4*)p;
  float4 b = *(const float4*)(p + 4);
  bf16x8 r;
  r[0] = (bf16_t)a.x; r[1] = (bf16_t)a.y; r[2] = (bf16_t)a.z; r[3] = (bf16_t)a.w;
  r[4] = (bf16_t)b.x; r[5] = (bf16_t)b.y; r[6] = (bf16_t)b.z; r[7] = (bf16_t)b.w;
  return r;
}

// async global -> LDS, 16B per lane; lds ptr must be wave-uniform (HW adds lane*16)
static __device__ __forceinline__ void gload16(const void* g, void* l) {
  __builtin_amdgcn_global_load_lds((__attribute__((address_space(1))) void*)(uintptr_t)g,
                                   (__attribute__((address_space(3))) void*)l, 16, 0, 0);
}

static __device__ __forceinline__ unsigned cvtpk(float lo, float hi) {
  unsigned r;
  asm("v_cvt_pk_bf16_f32 %0, %1, %2" : "=v"(r) : "v"(lo), "v"(hi));
  return r;
}

static __device__ __forceinline__ f32x16 zero16() {
  f32x16 z;
#pragma unroll
  for (int i = 0; i < 16; ++i) z[i] = 0.f;
  return z;
}

// ---------------- per-head projections + Wo convert, one launch (z selects) ----------------
// z=0: V -> Vt2[nh][l>>3][d][l&7]; z=1: K -> Kp[nh][l][d]; z=2: Q*scale -> Qp[nh][l][d];
// z=3: Wo fp32 -> bf16 (pure convert, early return, no barriers)
__global__ __launch_bounds__(256) void k_proj3(const float* __restrict__ Xv, const float* __restrict__ Xk,
                                               const float* __restrict__ Xq, const float* __restrict__ Wv,
                                               const float* __restrict__ Wk, const float* __restrict__ Wq,
                                               u16* __restrict__ Vt, u16* __restrict__ Kp, u16* __restrict__ Qp,
                                               const float* __restrict__ Wo, u16* __restrict__ Wob) {
  int z = blockIdx.z;
  if (z == 3) {   // whole block takes this path: no barrier divergence
    size_t i = ((size_t)blockIdx.x * 256 + threadIdx.x) * 8;
    V16 v; v.b = cvt8(Wo + i);
    *(uint4*)(Wob + i) = v.u;
    return;
  }
  __shared__ __align__(16) u16 xs[16 * 1024];
  __shared__ __align__(16) u16 obuf[4][16 * 72];
  __shared__ __align__(16) u16 ob2[4][1024];
  const float* X = (z == 0) ? Xv : (z == 1) ? Xk : Xq;
  const float* W = (z == 0) ? Wv : (z == 1) ? Wk : Wq;
  u16* Out = (z == 0) ? Vt : (z == 1) ? Kp : Qp;
  int vmode = (z == 0);
  float qs = (z == 2) ? 0.04508422f : 1.0f;   // (1/sqrt(EMB)) * log2(e) folded into Q

  int gr0 = blockIdx.x * 16;
  int n = gr0 >> 10, l0 = gr0 & 1023;
  int tid = threadIdx.x, w = tid >> 6, lane = tid & 63;
  int lr = lane & 15, lg = lane >> 4;

  bf16x8 bw[4][2];
#pragma unroll
  for (int c = 0; c < 4; ++c)
#pragma unroll
    for (int kk = 0; kk < 2; ++kk)
      bw[c][kk] = cvt8(W + (lr + 16 * c) * HD + kk * 32 + lg * 8);

#pragma unroll
  for (int i = 0; i < 8; ++i) {
    int m = i * 256 + tid;
    int row = m >> 7, cc = m & 127;
    V16 v; v.b = cvt8(X + (size_t)gr0 * 1024 + (size_t)m * 8);
    *(uint4*)(xs + row * 1024 + ((cc ^ (row & 7)) * 8)) = v.u;
  }
  __syncthreads();

#pragma unroll 1
  for (int h4 = 0; h4 < 4; ++h4) {
    int h = w * 4 + h4;
    int nh = n * 16 + h;
    bf16x8 a0 = ldb8(xs + lr * 1024 + (((h * 8 + 0 + lg) ^ (lr & 7)) * 8));
    bf16x8 a1 = ldb8(xs + lr * 1024 + (((h * 8 + 4 + lg) ^ (lr & 7)) * 8));
    f32x4 acc[4];
#pragma unroll
    for (int c = 0; c < 4; ++c) {
      f32x4 zz = {0.f, 0.f, 0.f, 0.f};
      zz = MFMA16(a0, bw[c][0], zz);
      zz = MFMA16(a1, bw[c][1], zz);
      acc[c] = zz;
    }
    if (!vmode) {
      u16* ob = obuf[w];
#pragma unroll
      for (int c = 0; c < 4; ++c)
#pragma unroll
        for (int rr = 0; rr < 4; ++rr)
          ob[(lg * 4 + rr) * 72 + lr + 16 * c] = f2b(acc[c][rr] * qs);
      int orow = lane >> 2, oseg = lane & 3;
      uint4 v0 = *(const uint4*)(ob + orow * 72 + oseg * 16);
      uint4 v1 = *(const uint4*)(ob + orow * 72 + oseg * 16 + 8);
      u16* dst = Out + ((size_t)nh * SEQL + l0 + orow) * HD + oseg * 16;
      *(uint4*)dst = v0;
      *(uint4*)(dst + 8) = v1;
    } else {
      u16* o2 = ob2[w];
#pragma unroll
      for (int c = 0; c < 4; ++c) {
        ushort4 p;
        p.x = f2b(acc[c][0]); p.y = f2b(acc[c][1]); p.z = f2b(acc[c][2]); p.w = f2b(acc[c][3]);
        *(ushort4*)(o2 + (lg >> 1) * 512 + (lr + 16 * c) * 8 + (lg & 1) * 4) = p;
      }
      int lb0 = l0 >> 3;
#pragma unroll
      for (int lbi = 0; lbi < 2; ++lbi) {
        uint4 vv = *(const uint4*)(o2 + lbi * 512 + lane * 8);
        *(uint4*)(Out + (size_t)nh * 65536 + (size_t)(lb0 + lbi) * 512 + lane * 8) = vv;
      }
    }
  }
}

// ---------------- fused attention: 4 waves x 64 q-rows, KV tiles of 64, dbuf ----------------
// Byte-exact R7/R11 (proven ~50 us): per-quadrant pipeline, serial lsum + shfl + winv epilogue.
// Five structural perturbations (KVBLK=128, 2-wave blocks, ones-MFMA denom, KV-split) all
// regressed vs this shape -> structure frozen. Rule #20: all oacc indices compile-time.
__global__ __launch_bounds__(256, 2) void k_attn2(const u16* __restrict__ Qp, const u16* __restrict__ Kp,
                                                  const u16* __restrict__ Vt, const int* __restrict__ mask,
                                                  u16* __restrict__ AO) {
  __shared__ __align__(16) u16 SMEM[2][8192];   // [buf][ K:0..4095 | V:4096..8191 ]
  __shared__ unsigned long long mkb[16];
  __shared__ __align__(16) float winv[4][2][32];

  int nh = blockIdx.x;
  int n = nh >> 4, h = nh & 15;
  int tid = threadIdx.x, w = tid >> 6, lane = tid & 63;
  int q = lane & 31, hi = lane >> 5;
  int q0w = blockIdx.y * 256 + w * 64;

  // Q B-frags for both q-groups (Q pre-scaled)
  bf16x8 bq[2][4];
#pragma unroll
  for (int g = 0; g < 2; ++g) {
    const u16* qbase = Qp + ((size_t)nh * SEQL + q0w + g * 32 + q) * HD + hi * 8;
#pragma unroll
    for (int kk = 0; kk < 4; ++kk) bq[g][kk] = ldb8(qbase + kk * 16);
  }

  const u16* gK = Kp + (size_t)nh * SEQL * HD;
  const u16* gV = Vt + (size_t)nh * HD * SEQL;
  int sr = lane >> 3, sslot = lane & 7;

  auto STAGE = [&](int b, int t) {
#pragma unroll
    for (int j = 0; j < 2; ++j) {
      int r = 16 * w + 8 * j + sr;              // tile row 0..63
      int slot = sslot ^ (r & 7);               // pre-swizzled source chunk
      gload16(gK + ((size_t)(t * 64 + r)) * HD + slot * 8,
              &SMEM[b][w * 1024 + j * 512]);
      // Vt2 chunked: element (d=r, l = t*64 + slot*8 + [0,8)) at (t*8+slot)*512 + r*8
      gload16(gV + (size_t)(t * 8 + slot) * 512 + r * 8,
              &SMEM[b][4096 + w * 1024 + j * 512]);
    }
  };

  STAGE(0, 0);
#pragma unroll 1
  for (int t = w; t < 16; t += 4) {
    int mv = mask[n * SEQL + t * 64 + lane];
    unsigned long long b = __ballot(mv != 0);
    if (lane == 0) mkb[t] = b;
  }
  __syncthreads();

  f32x16 oacc[2][2];
  oacc[0][0] = zero16(); oacc[0][1] = zero16();
  oacc[1][0] = zero16(); oacc[1][1] = zero16();
  float lsum0 = 0.f, lsum1 = 0.f;
  int buf = 0;

#pragma unroll 1
  for (int kt = 0; kt < 16; ++kt) {
    if (kt < 15) STAGE(buf ^ 1, kt + 1);
    const u16* KB = &SMEM[buf][0];
    const u16* VB = &SMEM[buf][4096];
    unsigned long long mb = mkb[kt];

#pragma unroll
    for (int c = 0; c < 2; ++c) {
      // ---- QK^T quadrant c: lane holds S[kpos=32c+4hi+(rr&3)+8(rr>>2)][q], both groups
      f32x16 s0 = zero16(), s1 = zero16();
      {
        int row = 32 * c + q;
        int swz = (row & 7) << 3;
        const u16* kr = KB + row * 64;
        __builtin_amdgcn_s_setprio(1);
#pragma unroll
        for (int kk = 0; kk < 4; ++kk) {
          bf16x8 ak = ldb8(kr + ((16 * kk + 8 * hi) ^ swz));
          s0 = MFMA32(ak, bq[0][kk], s0);
          s1 = MFMA32(ak, bq[1][kk], s1);
        }
        __builtin_amdgcn_s_setprio(0);
      }

      // ---- exp2 (Q pre-scaled, logits bounded) + mask + local denominator
#pragma unroll
      for (int rr = 0; rr < 16; ++rr) {
        s0[rr] = __builtin_amdgcn_exp2f(s0[rr]);
        s1[rr] = __builtin_amdgcn_exp2f(s1[rr]);
      }
      if (mb != ~0ull) {
#pragma unroll
        for (int rr = 0; rr < 16; ++rr) {
          int kpos = 32 * c + 4 * hi + (rr & 3) + 8 * (rr >> 2);
          if (!((mb >> kpos) & 1)) { s0[rr] = 0.f; s1[rr] = 0.f; }
        }
      }
#pragma unroll
      for (int rr = 0; rr < 16; ++rr) { lsum0 += s0[rr]; lsum1 += s1[rr]; }

      // ---- pack quadrant c to PV A-frags (tq = 2c+p2) via cvt_pk + permlane32_swap
      bf16x8 pa0[2], pa1[2];
#pragma unroll
      for (int p2 = 0; p2 < 2; ++p2) {
        unsigned a0 = cvtpk(s0[8 * p2 + 0], s0[8 * p2 + 1]);
        unsigned a1 = cvtpk(s0[8 * p2 + 2], s0[8 * p2 + 3]);
        unsigned b0 = cvtpk(s0[8 * p2 + 4], s0[8 * p2 + 5]);
        unsigned b1 = cvtpk(s0[8 * p2 + 6], s0[8 * p2 + 7]);
        auto r0 = __builtin_amdgcn_permlane32_swap(a0, b0, false, false);
        auto r1 = __builtin_amdgcn_permlane32_swap(a1, b1, false, false);
        union { unsigned u[4]; bf16x8 v; } pu;
        pu.u[0] = r0[0]; pu.u[1] = r1[0]; pu.u[2] = r0[1]; pu.u[3] = r1[1];
        pa0[p2] = pu.v;
        unsigned c0 = cvtpk(s1[8 * p2 + 0], s1[8 * p2 + 1]);
        unsigned c1 = cvtpk(s1[8 * p2 + 2], s1[8 * p2 + 3]);
        unsigned d0 = cvtpk(s1[8 * p2 + 4], s1[8 * p2 + 5]);
        unsigned d1 = cvtpk(s1[8 * p2 + 6], s1[8 * p2 + 7]);
        auto r2 = __builtin_amdgcn_permlane32_swap(c0, d0, false, false);
        auto r3 = __builtin_amdgcn_permlane32_swap(c1, d1, false, false);
        union { unsigned u[4]; bf16x8 v; } pv;
        pv.u[0] = r2[0]; pv.u[1] = r3[0]; pv.u[2] = r2[1]; pv.u[3] = r3[1];
        pa1[p2] = pv.v;
      }

      // ---- PV for tq in {2c, 2c+1}: V frag shared by both groups
      __builtin_amdgcn_s_setprio(1);
#pragma unroll
      for (int cp = 0; cp < 2; ++cp) {
        int row = 32 * cp + q;                   // d index
        int swz = (row & 7) << 3;
        const u16* vr = VB + row * 64;
#pragma unroll
        for (int p2 = 0; p2 < 2; ++p2) {
          int tq = 2 * c + p2;
          bf16x8 vb = ldb8(vr + ((16 * tq + 8 * hi) ^ swz));
          oacc[0][cp] = MFMA32(pa0[p2], vb, oacc[0][cp]);
          oacc[1][cp] = MFMA32(pa1[p2], vb, oacc[1][cp]);
        }
      }
      __builtin_amdgcn_s_setprio(0);
    }
    __syncthreads();
    buf ^= 1;
  }

  // denominators: q-row halves live on lane pair (q, q+32)
  float t0 = lsum0 + __shfl_xor(lsum0, 32);
  float t1 = lsum1 + __shfl_xor(lsum1, 32);
  if (!hi) { winv[w][0][q] = 1.0f / t0; winv[w][1][q] = 1.0f / t1; }

  // epilogue per q-group (fully unrolled; rule #20)
  u16* ob = &SMEM[0][0] + w * 2560;
  int orow = lane >> 1, ohalf = lane & 1;
#pragma unroll
  for (int g = 0; g < 2; ++g) {
    float iq[16];
#pragma unroll
    for (int w2 = 0; w2 < 4; ++w2) {
      float4 f = *(const float4*)&winv[w][g][8 * w2 + 4 * hi];
      iq[4 * w2 + 0] = f.x; iq[4 * w2 + 1] = f.y; iq[4 * w2 + 2] = f.z; iq[4 * w2 + 3] = f.w;
    }
#pragma unroll
    for (int cp = 0; cp < 2; ++cp)
#pragma unroll
      for (int rr = 0; rr < 16; ++rr) {
        int qr = (rr & 3) + 8 * (rr >> 2) + 4 * hi;
        ob[qr * 80 + 32 * cp + q] = f2b(oacc[g][cp][rr] * iq[rr]);
      }
    __builtin_amdgcn_s_barrier();
    const u16* srcp = ob + orow * 80 + ohalf * 32;
    uint4 v0 = *(const uint4*)srcp;
    uint4 v1 = *(const uint4*)(srcp + 8);
    uint4 v2 = *(const uint4*)(srcp + 16);
    uint4 v3 = *(const uint4*)(srcp + 24);
    u16* dst = AO + ((size_t)(n * SEQL + q0w + g * 32 + orow)) * EMB + h * HD + ohalf * 32;
    *(uint4*)dst = v0;
    *(uint4*)(dst + 8) = v1;
    *(uint4*)(dst + 16) = v2;
    *(uint4*)(dst + 24) = v3;
  }
}

// ---------------- output projection: Y = AO (8192x1024) * Wo^T + bo ----------------
__global__ __launch_bounds__(256) void k_out(const u16* __restrict__ AO, const u16* __restrict__ Wob,
                                             const float* __restrict__ bo, float* __restrict__ Y) {
  __shared__ __align__(16) u16 As[2][8192];
  __shared__ __align__(16) u16 Bs[2][8192];
  int g = blockIdx.x;
  int xcd = g & 7, rr_ = g >> 3;
  int m0 = (xcd * 8 + (rr_ >> 3)) * 128;
  int n0 = (rr_ & 7) * 128;
  int tid = threadIdx.x, w = tid >> 6, lane = tid & 63;
  int lr = lane & 15, lg = lane >> 4;
  int wr = w >> 1, wc = w & 1;
  int sr8 = lane >> 3, ss8 = lane & 7;

  auto STAGE = [&](int b, int kb) {
#pragma unroll
    for (int j = 0; j < 4; ++j) {
      int row = 32 * w + 8 * j + sr8;
      gload16(AO + (size_t)(m0 + row) * EMB + kb * 64 + ((ss8 ^ (row & 7)) * 8),
              &As[b][w * 2048 + j * 512]);
      gload16(Wob + (size_t)(n0 + row) * EMB + kb * 64 + ((ss8 ^ (row & 7)) * 8),
              &Bs[b][w * 2048 + j * 512]);
    }
  };

  f32x4 acc[4][4] = {};
  STAGE(0, 0);
  __syncthreads();
  int buf = 0;
#pragma unroll 1
  for (int kb = 0; kb < 16; ++kb) {
    if (kb < 15) STAGE(buf ^ 1, kb + 1);
    bf16x8 a0[4], a1[4], b0[4], b1[4];
#pragma unroll
    for (int mi = 0; mi < 4; ++mi) {
      int row = wr * 64 + mi * 16 + lr;
      a0[mi] = ldb8(&As[buf][row * 64 + (((0 + lg) ^ (row & 7)) * 8)]);
      a1[mi] = ldb8(&As[buf][row * 64 + (((4 + lg) ^ (row & 7)) * 8)]);
    }
#pragma unroll
    for (int ni = 0; ni < 4; ++ni) {
      int row = wc * 64 + ni * 16 + lr;
      b0[ni] = ldb8(&Bs[buf][row * 64 + (((0 + lg) ^ (row & 7)) * 8)]);
      b1[ni] = ldb8(&Bs[buf][row * 64 + (((4 + lg) ^ (row & 7)) * 8)]);
    }
    __builtin_amdgcn_s_setprio(1);
#pragma unroll
    for (int mi = 0; mi < 4; ++mi)
#pragma unroll
      for (int ni = 0; ni < 4; ++ni) {
        acc[mi][ni] = MFMA16(a0[mi], b0[ni], acc[mi][ni]);
        acc[mi][ni] = MFMA16(a1[mi], b1[ni], acc[mi][ni]);
      }
    __builtin_amdgcn_s_setprio(0);
    __syncthreads();
    buf ^= 1;
  }
#pragma unroll
  for (int ni = 0; ni < 4; ++ni) {
    float bov = bo[n0 + wc * 64 + ni * 16 + lr];
#pragma unroll
    for (int mi = 0; mi < 4; ++mi) {
#pragma unroll
      for (int rr = 0; rr < 4; ++rr) {
        int row = m0 + wr * 64 + mi * 16 + lg * 4 + rr;
        int col = n0 + wc * 64 + ni * 16 + lr;
        Y[(size_t)row * EMB + col] = acc[mi][ni][rr] + bov;
      }
    }
  }
}

extern "C" void kernel_launch(void* const* d_in, const int* in_sizes, int n_in,
                              void* d_out, int out_size, void* d_ws, size_t ws_size,
                              hipStream_t stream) {
  (void)in_sizes; (void)n_in; (void)out_size; (void)ws_size;
  const float* values = (const float*)d_in[0];
  const float* keys   = (const float*)d_in[1];
  const float* query  = (const float*)d_in[2];
  const int*   mask   = (const int*)d_in[3];
  const float* Wv = (const float*)d_in[4];
  const float* Wk = (const float*)d_in[5];
  const float* Wq = (const float*)d_in[6];
  const float* Wo = (const float*)d_in[7];
  const float* bo = (const float*)d_in[8];
  float* out = (float*)d_out;

  u16* ws  = (u16*)d_ws;
  u16* Qp  = ws;
  u16* Kp  = ws + (size_t)8 * 1024 * 1024;
  u16* Vt  = ws + (size_t)16 * 1024 * 1024;
  u16* AO  = ws + (size_t)24 * 1024 * 1024;
  u16* Wob = ws + (size_t)32 * 1024 * 1024;

  k_proj3<<<dim3(512, 1, 4), dim3(256), 0, stream>>>(values, keys, query, Wv, Wk, Wq, Vt, Kp, Qp, Wo, Wob);
  k_attn2<<<dim3(128, 4), dim3(256), 0, stream>>>(Qp, Kp, Vt, mask, AO);
  k_out<<<dim3(512), dim3(256), 0, stream>>>(AO, Wob, bo, out);
}